// Round 9
// baseline (58.837 us; speedup 1.0000x reference)
//
#include <hip/hip_runtime.h>
#include <hip/hip_bf16.h>

// TemporalCorrelation as band-GEMM on MFMA — ZERO-LDS K-loop, direct
// global->register fragment gathers, no barriers between chunks.
// out[b,o,t] = <f1[b,:,t], f2[b,:,clamp(t+o-10)]> / (||f1[:,t]|| ||f2[:,t']||)
// Block: 256 thr = 4 independent waves. Wave w: M-tile [t0+16w,16),
// B-tiles w,w+1,w+2 of the 96-col window. Fragment layout (verified r3):
// m/n = lane&15, k = 8*(lane>>4)+j  -> per-j dword load = 4 x 64B coalesced
// segments. Replicate-pad = per-lane clamp on B column (loop-invariant).
// Depth-2 in-register pipeline (64 outstanding loads ~ vmcnt budget).

constexpr int B  = 8;
constexpr int C  = 1024;
constexpr int T  = 4096;
constexpr int NO = 21;
constexpr int MD = 10;

typedef __attribute__((ext_vector_type(8))) short short8;
typedef __attribute__((ext_vector_type(4))) float f32x4;
typedef __attribute__((ext_vector_type(4))) unsigned int u32x4;

__device__ inline unsigned cvt2(float lo, float hi) {
    __hip_bfloat162 h = __float22bfloat162_rn(make_float2(lo, hi));
    return *reinterpret_cast<unsigned*>(&h);
}

struct Frag { float a[8]; float b0[8]; float b1[8]; float b2[8]; };

__global__ __launch_bounds__(256, 2)
void corr_direct(const float* __restrict__ f1, const float* __restrict__ f2,
                 float* __restrict__ out)
{
    __shared__ float inv1L[64];
    __shared__ float inv2L[96];
    __shared__ float outT[NO][68];

    const int sb   = (int)blockIdx.x;
    const int flat = (sb & 7) * 64 + (sb >> 3);    // XCD swizzle (512%8==0)
    const int b    = flat >> 6;
    const int t0   = (flat & 63) * 64;

    const int tid  = (int)threadIdx.x;
    const int lane = tid & 63;
    const int w    = tid >> 6;                     // wave id = M-tile id
    const int lm   = lane & 15;                    // m/n index within tile
    const int ks   = lane >> 4;                    // k-slot (8 channels)
    const int m0   = t0 + w * 16;

    // Per-lane loop-invariant element offsets (floats) within a chunk pane.
    // A: col m0+lm (folded into base); B: per-lane clamped window column.
    const float* f1b = f1 + (size_t)b * C * T + m0 + lm;
    const float* f2b = f2 + (size_t)b * C * T;
    int tp[3];
#pragma unroll
    for (int n = 0; n < 3; ++n)
        tp[n] = min(max(t0 - 16 + 16 * (w + n) + lm, 0), T - 1);

    f32x4 acc0 = {0.f,0.f,0.f,0.f}, acc1 = {0.f,0.f,0.f,0.f}, acc2 = {0.f,0.f,0.f,0.f};
    float sq1 = 0.f, sq2 = 0.f, sq2e = 0.f;

    auto load_chunk = [&](int k) {
        Frag F; const int cb = k * 32 * T;         // chunk base (<=4.1M, int ok)
#pragma unroll
        for (int j = 0; j < 8; ++j) {
            const int co = cb + (8 * ks + j) * T;
            F.a[j]  = f1b[co];
            F.b0[j] = f2b[co + tp[0]];
            F.b1[j] = f2b[co + tp[1]];
            F.b2[j] = f2b[co + tp[2]];
        }
        return F;
    };
    auto process = [&](const Frag& F) {
        u32x4 ua, u0, u1, u2;
#pragma unroll
        for (int i = 0; i < 4; ++i) {
            ua[i] = cvt2(F.a[2*i],  F.a[2*i+1]);
            u0[i] = cvt2(F.b0[2*i], F.b0[2*i+1]);
            u1[i] = cvt2(F.b1[2*i], F.b1[2*i+1]);
            u2[i] = cvt2(F.b2[2*i], F.b2[2*i+1]);
        }
        const short8 af = __builtin_bit_cast(short8, ua);
        acc0 = __builtin_amdgcn_mfma_f32_16x16x32_bf16(af, __builtin_bit_cast(short8, u0), acc0, 0, 0, 0);
        acc1 = __builtin_amdgcn_mfma_f32_16x16x32_bf16(af, __builtin_bit_cast(short8, u1), acc1, 0, 0, 0);
        acc2 = __builtin_amdgcn_mfma_f32_16x16x32_bf16(af, __builtin_bit_cast(short8, u2), acc2, 0, 0, 0);
#pragma unroll
        for (int j = 0; j < 8; ++j) {
            sq1 += F.a[j]  * F.a[j];
            sq2 += F.b1[j] * F.b1[j];              // center tile = own cols
        }
        if (w == 0) {
#pragma unroll
            for (int j = 0; j < 8; ++j) sq2e += F.b0[j] * F.b0[j];
        } else if (w == 3) {
#pragma unroll
            for (int j = 0; j < 8; ++j) sq2e += F.b2[j] * F.b2[j];
        }
    };

    // ---- depth-2 in-register pipeline, NO barriers, NO LDS ----
    Frag F0 = load_chunk(0), F1 = load_chunk(1);
    for (int k = 0; k < 32; k += 2) {
        process(F0);
        if (k + 2 < 32) F0 = load_chunk(k + 2);
        process(F1);
        if (k + 3 < 32) F1 = load_chunk(k + 3);
    }

    // ---- norms: 2 shuffles per scalar, then per-wave LDS publish ----
    sq1  += __shfl_xor(sq1, 16, 64);  sq1  += __shfl_xor(sq1, 32, 64);
    sq2  += __shfl_xor(sq2, 16, 64);  sq2  += __shfl_xor(sq2, 32, 64);
    sq2e += __shfl_xor(sq2e, 16, 64); sq2e += __shfl_xor(sq2e, 32, 64);
    if (lane < 16) {
        inv1L[w * 16 + lane]        = 1.f / fmaxf(sqrtf(sq1), 1e-12f);
        inv2L[16 * (w + 1) + lane]  = 1.f / fmaxf(sqrtf(sq2), 1e-12f);
        if (w == 0) inv2L[lane]      = 1.f / fmaxf(sqrtf(sq2e), 1e-12f);
        if (w == 3) inv2L[80 + lane] = 1.f / fmaxf(sqrtf(sq2e), 1e-12f);
    }
    __syncthreads();

    // ---- epilogue (verified r3): clamp-redirect -> outT, coalesced store ----
    const int cr  = lane & 15;            // N-col within tile
    const int rr4 = (lane >> 4) * 4;      // M-row base
#define EPI(nt, A)                                                          \
    {                                                                       \
        const int tpp = t0 - 16 + (w + (nt)) * 16 + cr;                     \
        _Pragma("unroll")                                                   \
        for (int r = 0; r < 4; ++r) {                                       \
            const int t = m0 + rr4 + r;                                     \
            const int d = tpp - t;                                          \
            if (tpp >= 0 && tpp < T && d >= -MD && d <= MD) {               \
                const float val = (A)[r] * inv1L[t - t0] * inv2L[tpp - t0 + 16]; \
                const int on  = d + MD;                                     \
                const int olo = (tpp == 0)     ? 0      : on;               \
                const int ohi = (tpp == T - 1) ? NO - 1 : on;               \
                for (int o = olo; o <= ohi; ++o) outT[o][t - t0] = val;     \
            }                                                               \
        }                                                                   \
    }
    EPI(0, acc0) EPI(1, acc1) EPI(2, acc2)
#undef EPI
    __syncthreads();

    for (int task = tid; task < NO * 16; task += 256) {
        const int o  = task >> 4;
        const int t4 = (task & 15) * 4;
        const float4 v = *(const float4*)&outT[o][t4];
        *(float4*)(out + ((size_t)b * NO + o) * T + t0 + t4) = v;
    }
}

extern "C" void kernel_launch(void* const* d_in, const int* in_sizes, int n_in,
                              void* d_out, int out_size, void* d_ws, size_t ws_size,
                              hipStream_t stream)
{
    const float* f1 = (const float*)d_in[0];
    const float* f2 = (const float*)d_in[1];
    (void)d_ws; (void)ws_size;
    corr_direct<<<dim3(512), dim3(256), 0, stream>>>(f1, f2, (float*)d_out);
}

// Round 10
// 46.071 us; speedup vs baseline: 1.2771x; 1.2771x over previous
//
#include <hip/hip_runtime.h>

// TemporalCorrelation as band-GEMM on MFMA — plain-HIP data path only.
// out[b,o,t] = <f1[b,:,t], f2[b,:,clamp(t+o-10)]> / (||f1[:,t]|| ||f2[:,t']||)
// Block: 256 thr (4 waves), tile = 64 t-cols x all 1024 channels.
// Wave w: M-tile [t0+16w,16), N-tiles w,w+1,w+2 of the 96-col f2 window.
// LDS tiles are [16 t][32 c] bf16 (fragment-major): A/B fragments are single
// ds_read_b128 per lane. fp32->bf16 transpose at store time via c-pair packed
// ds_write_b32. Slot-rotate swizzle on both sides keeps LDS <=4-way.
// VERIFIED BEST (round 3: 45.8 us = ~94% of the 6.29 TB/s fabric roofline
// applied to the irreducible 271 MB of traffic). Rounds 4-8 falsified every
// latency/occupancy/barrier/granularity theory — all structures converge to
// the same delivered bandwidth, so this is the memory-bound endpoint.

constexpr int B  = 8;
constexpr int C  = 1024;
constexpr int T  = 4096;
constexpr int NO = 21;
constexpr int MD = 10;

typedef __attribute__((ext_vector_type(8))) short short8;
typedef __attribute__((ext_vector_type(4))) float f32x4;

__device__ inline unsigned bf16rne(float f) {
    unsigned u = __float_as_uint(f);
    return (u + 0x7FFFu + ((u >> 16) & 1u)) >> 16;   // RNE bf16 in low 16
}
__device__ inline unsigned pack2(float lo, float hi) {
    return bf16rne(lo) | (bf16rne(hi) << 16);
}

struct Regs { float4 a0, a1, b0, b0b, b1, b1b; };

__global__ __launch_bounds__(256)
void corr_mfma(const float* __restrict__ f1, const float* __restrict__ f2,
               float* __restrict__ out)
{
    __shared__ short8 stgv[2][640];          // 2 x 5120 hw = 20 KB
    __shared__ float  sq1buf[64][17];
    __shared__ float  sq2buf[4][96];
    __shared__ float  inv1L[64];
    __shared__ float  inv2L[96];
    __shared__ float  outT[NO][68];

    const int sb   = (int)blockIdx.x;
    const int flat = (sb & 7) * 64 + (sb >> 3);    // XCD swizzle (512%8==0)
    const int b    = flat >> 6;
    const int t0   = (flat & 63) * 64;

    const int tid  = (int)threadIdx.x;
    const int lane = tid & 63;
    const int w    = tid >> 6;                     // wave id = M-tile id

    // ---- staging maps (constant across chunks) ----
    const int u1 = tid & 15;                       // f1 t-run (4 cols)
    const int q1 = tid >> 4;                       // f1 c-pair: rows 2q1,2q1+1
    const int r2 = tid & 15;                       // f2 window run (4 cols)
    const int q2 = tid >> 4;                       // f2 c-pair
    const bool x2 = (r2 < 8);                      // also stages run 16+r2

    const float* f1p = f1 + ((size_t)b * C + 2 * q1) * T + t0 + 4 * u1;
    const float* f2p = f2 + ((size_t)b * C + 2 * q2) * T;
    const int cA = min(max(t0 - 16 + 4 * r2,        0), T - 4);  // clamped src
    const int cB = min(max(t0 - 16 + 4 * (16 + r2), 0), T - 4);

    // store hw offsets: tile=[16t][32c], elem(t,c) at t*32 + slot'*8 + (c&7),
    // slot' = ((c>>3) + (t>>2)) & 3. Writes step +32 hw per t (i=0..3).
    const int f1hw = (u1 >> 2) * 512 + 4 * (u1 & 3) * 32
                   + ((((q1 >> 2) + (u1 & 3)) & 3) << 3) + 2 * (q1 & 3);
    const int f2hwA = 2048 + (r2 >> 2) * 512 + 4 * (r2 & 3) * 32
                    + ((((q2 >> 2) + (r2 & 3)) & 3) << 3) + 2 * (q2 & 3);
    const int f2hwB = f2hwA + 2048;               // run 16+r2: tile +4

    // fragment read offset: lane wants t=lane&15, c-slot=lane>>4
    const int ft  = lane & 15;
    const int fhw = ft * 32 + ((((lane >> 4) + (ft >> 2)) & 3) << 3);

    float sq1[4]  = {0.f, 0.f, 0.f, 0.f};
    float sq2a[4] = {0.f, 0.f, 0.f, 0.f};
    float sq2b[4] = {0.f, 0.f, 0.f, 0.f};
    f32x4 acc0 = {0.f,0.f,0.f,0.f}, acc1 = {0.f,0.f,0.f,0.f}, acc2 = {0.f,0.f,0.f,0.f};

    auto load_chunk = [&](int k) {
        Regs r; const size_t o = (size_t)k * 32 * T;
        r.a0  = *(const float4*)(f1p + o);
        r.a1  = *(const float4*)(f1p + o + T);
        r.b0  = *(const float4*)(f2p + o + cA);
        r.b0b = *(const float4*)(f2p + o + cA + T);
        if (x2) {
            r.b1  = *(const float4*)(f2p + o + cB);
            r.b1b = *(const float4*)(f2p + o + cB + T);
        }
        return r;
    };
    auto commit = [&](const Regs& r, int buf) {
        unsigned short* S = (unsigned short*)&stgv[buf][0];
        const float* a0 = (const float*)&r.a0;  const float* a1  = (const float*)&r.a1;
        const float* b0 = (const float*)&r.b0;  const float* b0b = (const float*)&r.b0b;
        const float* b1 = (const float*)&r.b1;  const float* b1b = (const float*)&r.b1b;
#pragma unroll
        for (int i = 0; i < 4; ++i) {
            *(unsigned*)&S[f1hw  + 32 * i] = pack2(a0[i], a1[i]);
            *(unsigned*)&S[f2hwA + 32 * i] = pack2(b0[i], b0b[i]);
            sq1[i]  += a0[i] * a0[i] + a1[i] * a1[i];
            sq2a[i] += b0[i] * b0[i] + b0b[i] * b0b[i];
        }
        if (x2) {
#pragma unroll
            for (int i = 0; i < 4; ++i) {
                *(unsigned*)&S[f2hwB + 32 * i] = pack2(b1[i], b1b[i]);
                sq2b[i] += b1[i] * b1[i] + b1b[i] * b1b[i];
            }
        }
    };
    auto compute = [&](int buf) {
        const unsigned short* S = (const unsigned short*)&stgv[buf][0];
        short8 af  = *(const short8*)&S[w * 512 + fhw];
        short8 bf0 = *(const short8*)&S[2048 + (w + 0) * 512 + fhw];
        short8 bf1 = *(const short8*)&S[2048 + (w + 1) * 512 + fhw];
        short8 bf2 = *(const short8*)&S[2048 + (w + 2) * 512 + fhw];
        acc0 = __builtin_amdgcn_mfma_f32_16x16x32_bf16(af, bf0, acc0, 0, 0, 0);
        acc1 = __builtin_amdgcn_mfma_f32_16x16x32_bf16(af, bf1, acc1, 0, 0, 0);
        acc2 = __builtin_amdgcn_mfma_f32_16x16x32_bf16(af, bf2, acc2, 0, 0, 0);
    };

    // ---- depth-2 pipelined K-loop, double-buffered LDS ----
    Regs RA = load_chunk(0), RB = load_chunk(1);
    for (int k = 0; k < 32; k += 2) {
        commit(RA, 0);
        __syncthreads();
        if (k + 2 < 32) RA = load_chunk(k + 2);
        compute(0);
        commit(RB, 1);
        __syncthreads();
        if (k + 3 < 32) RB = load_chunk(k + 3);
        compute(1);
    }

    // ---- norms ----
#pragma unroll
    for (int e = 0; e < 4; ++e) sq1buf[4 * u1 + e][q1] = sq1[e];
#pragma unroll
    for (int i = 0; i < 4; ++i) {
        sq2a[i] += __shfl_xor(sq2a[i], 16, 64);
        sq2a[i] += __shfl_xor(sq2a[i], 32, 64);
        sq2b[i] += __shfl_xor(sq2b[i], 16, 64);
        sq2b[i] += __shfl_xor(sq2b[i], 32, 64);
    }
    if (lane < 16) {
#pragma unroll
        for (int i = 0; i < 4; ++i) sq2buf[w][4 * lane + i] = sq2a[i];
    }
    if (lane < 8) {
#pragma unroll
        for (int i = 0; i < 4; ++i) sq2buf[w][64 + 4 * lane + i] = sq2b[i];
    }
    __syncthreads();
    if (tid < 64) {
        float s = 0.f;
#pragma unroll
        for (int g = 0; g < 16; ++g) s += sq1buf[tid][g];
        inv1L[tid] = 1.f / fmaxf(sqrtf(s), 1e-12f);
    } else if (tid < 160) {
        const int f = tid - 64;
        float s = sq2buf[0][f] + sq2buf[1][f] + sq2buf[2][f] + sq2buf[3][f];
        inv2L[f] = 1.f / fmaxf(sqrtf(s), 1e-12f);
    }
    __syncthreads();

    // ---- epilogue: band elems -> outT with clamp-redirect, then coalesced ----
    const int m0  = t0 + w * 16;
    const int cr  = lane & 15;            // N-col within tile
    const int rr4 = (lane >> 4) * 4;      // M-row base
#define EPI(nt, A)                                                          \
    {                                                                       \
        const int tp = t0 - 16 + (w + (nt)) * 16 + cr;                      \
        _Pragma("unroll")                                                   \
        for (int r = 0; r < 4; ++r) {                                       \
            const int t = m0 + rr4 + r;                                     \
            const int d = tp - t;                                           \
            if (tp >= 0 && tp < T && d >= -MD && d <= MD) {                 \
                const float val = (A)[r] * inv1L[t - t0] * inv2L[tp - t0 + 16]; \
                const int on  = d + MD;                                     \
                const int olo = (tp == 0)     ? 0      : on;                \
                const int ohi = (tp == T - 1) ? NO - 1 : on;                \
                for (int o = olo; o <= ohi; ++o) outT[o][t - t0] = val;     \
            }                                                               \
        }                                                                   \
    }
    EPI(0, acc0) EPI(1, acc1) EPI(2, acc2)
#undef EPI
    __syncthreads();

    for (int task = tid; task < NO * 16; task += 256) {
        const int o  = task >> 4;
        const int t4 = (task & 15) * 4;
        const float4 v = *(const float4*)&outT[o][t4];
        *(float4*)(out + ((size_t)b * NO + o) * T + t0 + t4) = v;
    }
}

extern "C" void kernel_launch(void* const* d_in, const int* in_sizes, int n_in,
                              void* d_out, int out_size, void* d_ws, size_t ws_size,
                              hipStream_t stream)
{
    const float* f1 = (const float*)d_in[0];
    const float* f2 = (const float*)d_in[1];
    (void)d_ws; (void)ws_size;
    corr_mfma<<<dim3(512), dim3(256), 0, stream>>>(f1, f2, (float*)d_out);
}